// Round 5
// baseline (343.124 us; speedup 1.0000x reference)
//
#include <hip/hip_runtime.h>
#include <stdint.h>

// SelfAttentionV3: out = softmax(mask(QK^T/32)) V, Q=Xq Wq+bq etc.
// B=8, S=2048, D=1024. GEMMs: bf16 MFMA, 256x256 tile, BK=64, 8-phase
// schedule (T3+T4 counted vmcnt), XOR-swizzled LDS (T2), setprio (T5),
// base+imm-offset ds_read addressing (HK technique 5/8) to kill VALU remat.
//
// ws layout (bytes):
//   [0,    32M)  q_bf16  [16384][1024]
//   [32M,  64M)  k_bf16  [16384][1024]
//   [64M,  96M)  vT_bf16 [8][1024][2048]
//   [96M, 192M)  A_bf16 converted inputs (dead after projections)
//   [192M,198M)  WT_bf16 transposed weights (dead after projections)
//   [96M, 163M)  scores/P bf16 [8][2048][2048] (overlays A region)

typedef unsigned short u16;
typedef __attribute__((ext_vector_type(8))) short short8;
typedef __attribute__((ext_vector_type(4))) float f32x4;

__device__ __forceinline__ u16 f2bf(float x) {
  unsigned u = __float_as_uint(x);
  return (u16)((u + 0x7FFFu + ((u >> 16) & 1u)) >> 16);  // RNE
}
__device__ __forceinline__ float bf2f(u16 h) {
  return __uint_as_float(((unsigned)h) << 16);
}

__device__ __forceinline__ void stage16(const void* g, void* l) {
  const __attribute__((address_space(1))) uint32_t* gp =
      (const __attribute__((address_space(1))) uint32_t*)(uintptr_t)g;
  __attribute__((address_space(3))) uint32_t* lp =
      (__attribute__((address_space(3))) uint32_t*)(uintptr_t)l;
  __builtin_amdgcn_global_load_lds(gp, lp, 16, 0, 0);
}

__device__ __forceinline__ short8 ld8(const char* p, int off) {
  return *(const short8*)(p + off);  // off is compile-time -> ds offset: imm
}

__global__ __launch_bounds__(256) void cvt(const float4* __restrict__ in,
                                           ushort4* __restrict__ out, int n4) {
  int stride = gridDim.x * blockDim.x;
  for (int i = blockIdx.x * blockDim.x + threadIdx.x; i < n4; i += stride) {
    float4 f = in[i];
    ushort4 o;
    o.x = f2bf(f.x); o.y = f2bf(f.y); o.z = f2bf(f.z); o.w = f2bf(f.w);
    out[i] = o;
  }
}

__global__ __launch_bounds__(256) void wtrans(const float* __restrict__ W,
                                              u16* __restrict__ WT) {
  __shared__ float tile[32][33];
  const int tx = threadIdx.x, ty = threadIdx.y;  // 32 x 8
  const int d0 = blockIdx.y * 32, n0 = blockIdx.x * 32;
#pragma unroll
  for (int i = 0; i < 4; ++i)
    tile[ty + 8 * i][tx] = W[(size_t)(d0 + ty + 8 * i) * 1024 + n0 + tx];
  __syncthreads();
#pragma unroll
  for (int i = 0; i < 4; ++i)
    WT[(size_t)(n0 + ty + 8 * i) * 1024 + d0 + tx] = f2bf(tile[tx][ty + 8 * i]);
}

// ---- 8-phase 256x256 GEMM: C = A * B^T, both bf16 K-contiguous ----
// 512 thr = 8 waves (2M x 4N), wave tile 128x64, BK=64, 2 K-tile LDS bufs.
// LDS per buf: A 256x64 @ +0 (r*8192 per 64-row group), B @ +32768; buf1 +65536.
// Swizzle: phys_colByte = logical ^ ((row&7)<<4), both-sides involution.

#define BAR __builtin_amdgcn_s_barrier()
#define SB __builtin_amdgcn_sched_barrier(0)

#define RDA(K0, K1, MH)                                     \
  {                                                         \
    _Pragma("unroll") for (int mf_ = 0; mf_ < 4; ++mf_) {   \
      afr[0][mf_] = ld8(K0, (MH) * 8192 + mf_ * 2048);      \
      afr[1][mf_] = ld8(K1, (MH) * 8192 + mf_ * 2048);      \
    }                                                       \
  }

#define RDB(DST, K0, K1, NH)                                \
  {                                                         \
    _Pragma("unroll") for (int nf_ = 0; nf_ < 2; ++nf_) {   \
      DST[0][nf_] = ld8(K0, (NH) * 4096 + nf_ * 2048);      \
      DST[1][nf_] = ld8(K1, (NH) * 4096 + nf_ * 2048);      \
    }                                                       \
  }

#define MFMAQ(ACC, NH, BARR)                                             \
  __builtin_amdgcn_s_setprio(1);                                         \
  {                                                                      \
    _Pragma("unroll") for (int ks_ = 0; ks_ < 2; ++ks_)                  \
        _Pragma("unroll") for (int mf_ = 0; mf_ < 4; ++mf_)              \
            _Pragma("unroll") for (int nf_ = 0; nf_ < 2; ++nf_)          \
                ACC[mf_][(NH) * 2 + nf_] =                               \
                    __builtin_amdgcn_mfma_f32_16x16x32_bf16(             \
                        afr[ks_][mf_], BARR[ks_][nf_],                   \
                        ACC[mf_][(NH) * 2 + nf_], 0, 0, 0);              \
  }                                                                      \
  __builtin_amdgcn_s_setprio(0);

template <int MODE>
__global__ __launch_bounds__(512, 2) void gemm8p(
    const u16* __restrict__ A, const u16* __restrict__ B,
    const float* __restrict__ bias, void* __restrict__ C,
    int K, int lda, int ldb, int ldc, int nbn,
    size_t Az, size_t Bz, size_t Cz) {
  __shared__ __attribute__((aligned(16))) char smem[131072];
  const int tid = threadIdx.x;
  const int lane = tid & 63;
  const int w = tid >> 6;     // 0..7
  const int wr = w >> 2;      // 0..1 (M)
  const int wc = w & 3;       // 0..3 (N)

  // XCD-aware bijective remap (nwg % 8 == 0 for all grids), bn-fastest.
  const int nwg = gridDim.x;
  const int cpx = nwg >> 3;
  int flat = blockIdx.x;
  flat = (flat & 7) * cpx + (flat >> 3);
  const int bn = flat % nbn;
  const int bm = flat / nbn;
  const int z = blockIdx.y;
  A += (size_t)z * Az;
  B += (size_t)z * Bz;

  // staging: thread covers row (r*64 + srow), 16B at phys col (lane&7)*16;
  // global source col inverse-swizzled (both-sides involution).
  const int srow = w * 8 + (lane >> 3);
  const int scol = ((lane & 7) ^ (lane >> 3)) << 3;  // elems
  const u16* Ab0 = A + (size_t)(bm * 256 + srow) * lda + scol;
  const u16* Ab1 = Ab0 + (size_t)64 * lda;
  const u16* Ab2 = Ab0 + (size_t)128 * lda;
  const u16* Ab3 = Ab0 + (size_t)192 * lda;
  const u16* Bb0 = B + (size_t)(bn * 256 + srow) * ldb + scol;
  const u16* Bb1 = Bb0 + (size_t)64 * ldb;
  const u16* Bb2 = Bb0 + (size_t)128 * ldb;
  const u16* Bb3 = Bb0 + (size_t)192 * ldb;
  char* ldsB = smem + w * 1024;  // wave-uniform stage base; HW adds lane*16

  // fragment read addressing: 8 loop-invariant base pointers, all other
  // indexing folded into compile-time ds offsets.
  const int fr = lane & 15;
  const int fq = lane >> 4;
  const int fx = (fr & 7) << 4;
  const char* pak0 = smem + wr * 16384 + fr * 128 + ((fq * 16) ^ fx);
  const char* pak1 = smem + wr * 16384 + fr * 128 + ((64 + fq * 16) ^ fx);
  const char* pak0b = pak0 + 65536;
  const char* pak1b = pak1 + 65536;
  const char* pbk0 = smem + 32768 + wc * 8192 + fr * 128 + ((fq * 16) ^ fx);
  const char* pbk1 = smem + 32768 + wc * 8192 + fr * 128 + ((64 + fq * 16) ^ fx);
  const char* pbk0b = pbk0 + 65536;
  const char* pbk1b = pbk1 + 65536;

  f32x4 acc0[4][4] = {};  // mh=0 rows
  f32x4 acc1[4][4] = {};  // mh=1 rows
  short8 afr[2][4], bf0[2][2], bf1[2][2];

  const int half = K >> 7;  // iterations; 2 K-tiles each

  // prologue: tile0 -> buf0 (first 8 loads), tile1 -> buf1
  stage16(Bb0, ldsB + 32768); stage16(Bb1, ldsB + 40960);
  stage16(Bb2, ldsB + 49152); stage16(Bb3, ldsB + 57344);
  stage16(Ab0, ldsB + 0);     stage16(Ab1, ldsB + 8192);
  stage16(Ab2, ldsB + 16384); stage16(Ab3, ldsB + 24576);
  stage16(Bb0 + 64, ldsB + 98304);  stage16(Bb1 + 64, ldsB + 106496);
  stage16(Bb2 + 64, ldsB + 114688); stage16(Bb3 + 64, ldsB + 122880);
  stage16(Ab0 + 64, ldsB + 65536);  stage16(Ab1 + 64, ldsB + 73728);
  stage16(Ab2 + 64, ldsB + 81920);  stage16(Ab3 + 64, ldsB + 90112);
  asm volatile("s_waitcnt vmcnt(8)" ::: "memory");  // tile0 landed
  BAR;

  int kto = 128;  // uniform elem offset of tile kt2 (= 2i+2)
  for (int i = 0; i < half; ++i) {
    const bool st = (i + 1 < half);
    // ph1: Q(t0,m0,n0)
    RDA(pak0, pak1, 0);
    RDB(bf0, pbk0, pbk1, 0);
    SB; BAR; MFMAQ(acc0, 0, bf0); BAR;
    // ph2: Q(t0,m0,n1)
    RDB(bf1, pbk0, pbk1, 1);
    SB; BAR; MFMAQ(acc0, 1, bf1); BAR;
    // ph3: Q(t0,m1,n0); B(t0) slots free after ph2 -> restage
    RDA(pak0, pak1, 1);
    if (st) { stage16(Bb0 + kto, ldsB + 32768); stage16(Bb1 + kto, ldsB + 40960); }
    SB; BAR; MFMAQ(acc1, 0, bf0); BAR;
    // ph4: Q(t0,m1,n1)
    if (st) { stage16(Bb2 + kto, ldsB + 49152); stage16(Bb3 + kto, ldsB + 57344); }
    SB; BAR; MFMAQ(acc1, 1, bf1);
    if (st) { asm volatile("s_waitcnt vmcnt(4)" ::: "memory"); }
    else    { asm volatile("s_waitcnt vmcnt(0)" ::: "memory"); }
    BAR;  // t1 fully landed
    // ph5: Q(t1,m0,n0); A(t0) slots free after ph3 -> restage
    RDA(pak0b, pak1b, 0);
    RDB(bf0, pbk0b, pbk1b, 0);
    if (st) { stage16(Ab0 + kto, ldsB + 0); stage16(Ab1 + kto, ldsB + 8192); }
    SB; BAR; MFMAQ(acc0, 0, bf0); BAR;
    // ph6: Q(t1,m0,n1)
    RDB(bf1, pbk0b, pbk1b, 1);
    if (st) { stage16(Ab2 + kto, ldsB + 16384); stage16(Ab3 + kto, ldsB + 24576); }
    SB; BAR; MFMAQ(acc0, 1, bf1); BAR;
    // ph7: Q(t1,m1,n0); B(t1) slots free after ph6
    RDA(pak0b, pak1b, 1);
    if (st) {
      stage16(Bb0 + kto + 64, ldsB + 98304);  stage16(Bb1 + kto + 64, ldsB + 106496);
      stage16(Bb2 + kto + 64, ldsB + 114688); stage16(Bb3 + kto + 64, ldsB + 122880);
    }
    SB; BAR; MFMAQ(acc1, 0, bf0); BAR;
    // ph8: Q(t1,m1,n1); A(t1) slots free after ph7
    if (st) {
      stage16(Ab0 + kto + 64, ldsB + 65536); stage16(Ab1 + kto + 64, ldsB + 73728);
      stage16(Ab2 + kto + 64, ldsB + 81920); stage16(Ab3 + kto + 64, ldsB + 90112);
    }
    SB; BAR; MFMAQ(acc1, 1, bf1);
    asm volatile("s_waitcnt vmcnt(8)" ::: "memory");  // next t0 landed
    BAR;
    kto += 128;
  }

  // D layout per 16x16 frag: col = fr, row = fq*4 + j.
  const int colb = bn * 256 + wc * 64 + fr;
#pragma unroll
  for (int mh = 0; mh < 2; ++mh) {
    f32x4(&ac)[4][4] = mh ? acc1 : acc0;
    const int rowb = bm * 256 + wr * 128 + mh * 64 + fq * 4;
    if constexpr (MODE == 0) {
      u16* Cb = (u16*)C;
#pragma unroll
      for (int mf = 0; mf < 4; ++mf)
#pragma unroll
        for (int n = 0; n < 4; ++n) {
          const int c = colb + n * 16;
          const float bv = bias[c];
#pragma unroll
          for (int j = 0; j < 4; ++j)
            Cb[(size_t)(rowb + mf * 16 + j) * ldc + c] = f2bf(ac[mf][n][j] + bv);
        }
    } else if constexpr (MODE == 1) {
      u16* Cb = (u16*)C;  // vT [8][1024][2048]
#pragma unroll
      for (int mf = 0; mf < 4; ++mf) {
        const int s0r = rowb + mf * 16;
        const int b_ = s0r >> 11;
        const int s_ = s0r & 2047;
#pragma unroll
        for (int n = 0; n < 4; ++n) {
          const int c = colb + n * 16;
          const float bv = bias[c];
          ushort4 o;
          o.x = f2bf(ac[mf][n][0] + bv);
          o.y = f2bf(ac[mf][n][1] + bv);
          o.z = f2bf(ac[mf][n][2] + bv);
          o.w = f2bf(ac[mf][n][3] + bv);
          *(ushort4*)&Cb[((size_t)b_ * 1024 + c) * 2048 + s_] = o;
        }
      }
    } else if constexpr (MODE == 2) {
      u16* Cb = (u16*)C + (size_t)z * Cz;
#pragma unroll
      for (int mf = 0; mf < 4; ++mf)
#pragma unroll
        for (int n = 0; n < 4; ++n) {
          const int c = colb + n * 16;
#pragma unroll
          for (int j = 0; j < 4; ++j)
            Cb[(size_t)(rowb + mf * 16 + j) * ldc + c] =
                f2bf(ac[mf][n][j] * 0.03125f);
        }
    } else {
      float* Cb = (float*)C + (size_t)z * Cz;
#pragma unroll
      for (int mf = 0; mf < 4; ++mf)
#pragma unroll
        for (int n = 0; n < 4; ++n) {
          const int c = colb + n * 16;
#pragma unroll
          for (int j = 0; j < 4; ++j)
            Cb[(size_t)(rowb + mf * 16 + j) * ldc + c] = ac[mf][n][j];
        }
    }
  }
}

// Masked row softmax over bf16 scores [2048]; writes P bf16 in place.
__global__ __launch_bounds__(256) void softmax_mask(u16* __restrict__ scores,
                                                    const int* __restrict__ mask) {
  const int row = blockIdx.x, b = blockIdx.y;
  const int t = threadIdx.x, lane = t & 63, w = t >> 6;
  u16* sc = scores + ((size_t)(b * 2048 + row) << 11);
  const int mrow = mask[b * 2048 + row];
  if (mrow == 0) {
    const u16 pv = f2bf(1.0f / 2048.0f);
    ushort4 o;
    o.x = o.y = o.z = o.w = pv;
    *(ushort4*)&sc[t * 8] = o;
    *(ushort4*)&sc[t * 8 + 4] = o;
    return;
  }
  const ushort4 h0 = ((const ushort4*)sc)[t * 2];
  const ushort4 h1 = ((const ushort4*)sc)[t * 2 + 1];
  const int4 m0 = ((const int4*)(mask + b * 2048))[t * 2];
  const int4 m1 = ((const int4*)(mask + b * 2048))[t * 2 + 1];
  float v[8] = {bf2f(h0.x), bf2f(h0.y), bf2f(h0.z), bf2f(h0.w),
                bf2f(h1.x), bf2f(h1.y), bf2f(h1.z), bf2f(h1.w)};
  const int mm[8] = {m0.x, m0.y, m0.z, m0.w, m1.x, m1.y, m1.z, m1.w};
  float lmax = -3.0e38f;
#pragma unroll
  for (int i = 0; i < 8; ++i)
    if (mm[i]) lmax = fmaxf(lmax, v[i]);
#pragma unroll
  for (int off = 32; off >= 1; off >>= 1) lmax = fmaxf(lmax, __shfl_xor(lmax, off));
  __shared__ float red[8];
  if (lane == 0) red[w] = lmax;
  __syncthreads();
  const float bmax = fmaxf(fmaxf(red[0], red[1]), fmaxf(red[2], red[3]));
  float e[8];
  float lsum = 0.f;
#pragma unroll
  for (int i = 0; i < 8; ++i) {
    e[i] = mm[i] ? __expf(v[i] - bmax) : 0.f;
    lsum += e[i];
  }
#pragma unroll
  for (int off = 32; off >= 1; off >>= 1) lsum += __shfl_xor(lsum, off);
  if (lane == 0) red[4 + w] = lsum;
  __syncthreads();
  const float inv = 1.0f / ((red[4] + red[5]) + (red[6] + red[7]));
  ushort4 o0, o1;
  o0.x = f2bf(e[0] * inv); o0.y = f2bf(e[1] * inv);
  o0.z = f2bf(e[2] * inv); o0.w = f2bf(e[3] * inv);
  o1.x = f2bf(e[4] * inv); o1.y = f2bf(e[5] * inv);
  o1.z = f2bf(e[6] * inv); o1.w = f2bf(e[7] * inv);
  *(ushort4*)&sc[t * 8] = o0;
  *(ushort4*)&sc[t * 8 + 4] = o1;
}

extern "C" void kernel_launch(void* const* d_in, const int* in_sizes, int n_in,
                              void* d_out, int out_size, void* d_ws, size_t ws_size,
                              hipStream_t stream) {
  const float* in_q = (const float*)d_in[0];
  const float* in_k = (const float*)d_in[1];
  const float* in_v = (const float*)d_in[2];
  const int* mask = (const int*)d_in[3];
  const float* Wq = (const float*)d_in[4];
  const float* bq = (const float*)d_in[5];
  const float* Wk = (const float*)d_in[6];
  const float* bk = (const float*)d_in[7];
  const float* Wv = (const float*)d_in[8];
  const float* bv = (const float*)d_in[9];

  char* ws = (char*)d_ws;
  const size_t SZ = (size_t)16384 * 1024 * 2;  // 32M bytes
  u16* qb = (u16*)(ws);
  u16* kb = (u16*)(ws + SZ);
  u16* vT = (u16*)(ws + 2 * SZ);
  u16* Aq = (u16*)(ws + 3 * SZ);
  u16* Ak = (u16*)(ws + 4 * SZ);
  u16* Av = (u16*)(ws + 5 * SZ);
  u16* WqT = (u16*)(ws + 6 * SZ);
  u16* WkT = WqT + 1024 * 1024;
  u16* WvT = WkT + 1024 * 1024;
  u16* scores = (u16*)(ws + 3 * SZ);  // bf16 [8][2048][2048], overlays A region

  // 1) converts
  const int n4 = 16384 * 1024 / 4;
  cvt<<<2048, 256, 0, stream>>>((const float4*)in_q, (ushort4*)Aq, n4);
  cvt<<<2048, 256, 0, stream>>>((const float4*)in_k, (ushort4*)Ak, n4);
  cvt<<<2048, 256, 0, stream>>>((const float4*)in_v, (ushort4*)Av, n4);
  dim3 wtb(32, 8);
  wtrans<<<dim3(32, 32), wtb, 0, stream>>>(Wq, WqT);
  wtrans<<<dim3(32, 32), wtb, 0, stream>>>(Wk, WkT);
  wtrans<<<dim3(32, 32), wtb, 0, stream>>>(Wv, WvT);

  // 2) projections: 64 bm x 4 bn = 256 blocks
  gemm8p<0><<<dim3(256, 1), 512, 0, stream>>>(Aq, WqT, bq, qb, 1024, 1024, 1024,
                                              1024, 4, 0, 0, 0);
  gemm8p<0><<<dim3(256, 1), 512, 0, stream>>>(Ak, WkT, bk, kb, 1024, 1024, 1024,
                                              1024, 4, 0, 0, 0);
  gemm8p<1><<<dim3(256, 1), 512, 0, stream>>>(Av, WvT, bv, vT, 1024, 1024, 1024,
                                              2048, 4, 0, 0, 0);

  // 3) scores[b] = q[b] k[b]^T / 32 ; per batch 8 bm x 8 bn = 64 blocks
  gemm8p<2><<<dim3(64, 8), 512, 0, stream>>>(
      qb, kb, nullptr, scores, 1024, 1024, 1024, 2048, 8,
      (size_t)2048 * 1024, (size_t)2048 * 1024, (size_t)2048 * 2048);

  // 4) masked softmax -> P bf16 in place
  softmax_mask<<<dim3(2048, 8), 256, 0, stream>>>(scores, mask);

  // 5) out[b] = P[b] vT[b]^T ; per batch 8 bm x 4 bn = 32 blocks
  gemm8p<3><<<dim3(32, 8), 512, 0, stream>>>(
      scores, vT, nullptr, d_out, 2048, 2048, 2048, 1024, 4,
      (size_t)2048 * 2048, (size_t)1024 * 2048, (size_t)2048 * 1024);
}

// Round 6
// 337.805 us; speedup vs baseline: 1.0157x; 1.0157x over previous
//
#include <hip/hip_runtime.h>
#include <stdint.h>

// SelfAttentionV3: out = softmax(mask(QK^T/32)) V, Q=Xq Wq+bq etc.
// B=8, S=2048, D=1024. GEMMs: bf16 MFMA, 256x256 tile, BK=64, 8-phase
// schedule (T3+T4 counted vmcnt), XOR-swizzled LDS (T2), setprio (T5),
// batch->XCD grid mapping for L2-resident staging (scores/PV).
//
// ws layout (bytes):
//   [0,    32M)  q_bf16  [16384][1024]
//   [32M,  64M)  k_bf16  [16384][1024]
//   [64M,  96M)  vT_bf16 [8][1024][2048]
//   [96M, 192M)  A_bf16 converted inputs (dead after projections)
//   [192M,198M)  WT_bf16 transposed weights (dead after projections)
//   [96M, 163M)  scores/P bf16 [8][2048][2048] (overlays A region)

typedef unsigned short u16;
typedef __attribute__((ext_vector_type(8))) short short8;
typedef __attribute__((ext_vector_type(4))) float f32x4;

__device__ __forceinline__ u16 f2bf(float x) {
  unsigned u = __float_as_uint(x);
  return (u16)((u + 0x7FFFu + ((u >> 16) & 1u)) >> 16);  // RNE
}
__device__ __forceinline__ float bf2f(u16 h) {
  return __uint_as_float(((unsigned)h) << 16);
}

__device__ __forceinline__ void stage16(const void* g, void* l) {
  const __attribute__((address_space(1))) uint32_t* gp =
      (const __attribute__((address_space(1))) uint32_t*)(uintptr_t)g;
  __attribute__((address_space(3))) uint32_t* lp =
      (__attribute__((address_space(3))) uint32_t*)(uintptr_t)l;
  __builtin_amdgcn_global_load_lds(gp, lp, 16, 0, 0);
}

__device__ __forceinline__ short8 ld8(const char* p, int off) {
  return *(const short8*)(p + off);  // off compile-time -> ds offset: imm
}

__global__ __launch_bounds__(256) void cvt(const float4* __restrict__ in,
                                           ushort4* __restrict__ out, int n4) {
  int stride = gridDim.x * blockDim.x;
  for (int i = blockIdx.x * blockDim.x + threadIdx.x; i < n4; i += stride) {
    float4 f = in[i];
    ushort4 o;
    o.x = f2bf(f.x); o.y = f2bf(f.y); o.z = f2bf(f.z); o.w = f2bf(f.w);
    out[i] = o;
  }
}

__global__ __launch_bounds__(256) void wtrans(const float* __restrict__ W,
                                              u16* __restrict__ WT) {
  __shared__ float tile[32][33];
  const int tx = threadIdx.x, ty = threadIdx.y;  // 32 x 8
  const int d0 = blockIdx.y * 32, n0 = blockIdx.x * 32;
#pragma unroll
  for (int i = 0; i < 4; ++i)
    tile[ty + 8 * i][tx] = W[(size_t)(d0 + ty + 8 * i) * 1024 + n0 + tx];
  __syncthreads();
#pragma unroll
  for (int i = 0; i < 4; ++i)
    WT[(size_t)(n0 + ty + 8 * i) * 1024 + d0 + tx] = f2bf(tile[tx][ty + 8 * i]);
}

// ---- 8-phase 256x256 GEMM: C = A * B^T, both bf16 K-contiguous ----
// 512 thr = 8 waves (2M x 4N), wave tile 128x64, BK=64, 2 K-tile LDS bufs.
// Swizzle: phys_colByte = logical ^ ((row&7)<<4), both-sides involution.
// GMAP 0: chunked XCD remap, z = blockIdx.y. GMAP 1: batch-per-XCD
//   (z = blockIdx.x & 7, bijective; L2-resident K-slice lockstep).

#define BAR __builtin_amdgcn_s_barrier()

#define RDA(K0, K1, MH)                                     \
  {                                                         \
    _Pragma("unroll") for (int mf_ = 0; mf_ < 4; ++mf_) {   \
      afr[0][mf_] = ld8(K0, (MH) * 8192 + mf_ * 2048);      \
      afr[1][mf_] = ld8(K1, (MH) * 8192 + mf_ * 2048);      \
    }                                                       \
  }

#define RDB(DST, K0, K1, NH)                                \
  {                                                         \
    _Pragma("unroll") for (int nf_ = 0; nf_ < 2; ++nf_) {   \
      DST[0][nf_] = ld8(K0, (NH) * 4096 + nf_ * 2048);      \
      DST[1][nf_] = ld8(K1, (NH) * 4096 + nf_ * 2048);      \
    }                                                       \
  }

#define MFMAQ(ACC, NH, BARR)                                             \
  __builtin_amdgcn_s_setprio(1);                                         \
  {                                                                      \
    _Pragma("unroll") for (int ks_ = 0; ks_ < 2; ++ks_)                  \
        _Pragma("unroll") for (int mf_ = 0; mf_ < 4; ++mf_)              \
            _Pragma("unroll") for (int nf_ = 0; nf_ < 2; ++nf_)          \
                ACC[mf_][(NH) * 2 + nf_] =                               \
                    __builtin_amdgcn_mfma_f32_16x16x32_bf16(             \
                        afr[ks_][mf_], BARR[ks_][nf_],                   \
                        ACC[mf_][(NH) * 2 + nf_], 0, 0, 0);              \
  }                                                                      \
  __builtin_amdgcn_s_setprio(0);

template <int MODE, int GMAP>
__global__ __launch_bounds__(512, 2) void gemm8p(
    const u16* __restrict__ A, const u16* __restrict__ B,
    const float* __restrict__ bias, void* __restrict__ C,
    int K, int lda, int ldb, int ldc, int nbn,
    size_t Az, size_t Bz, size_t Cz) {
  __shared__ __attribute__((aligned(16))) char smem[131072];
  const int tid = threadIdx.x;
  const int lane = tid & 63;
  const int w = tid >> 6;     // 0..7
  const int wr = w >> 2;      // 0..1 (M)
  const int wc = w & 3;       // 0..3 (N)

  int bm, bn, z;
  if constexpr (GMAP == 0) {
    // chunked XCD remap (nwg % 8 == 0), bn-fastest within chunk
    const int nwg = gridDim.x;
    const int cpx = nwg >> 3;
    int flat = blockIdx.x;
    flat = (flat & 7) * cpx + (flat >> 3);
    bn = flat % nbn;
    bm = flat / nbn;
    z = blockIdx.y;
  } else {
    // batch-per-XCD: bijective; assumes RR xcd = blockIdx % 8 (perf-only)
    z = blockIdx.x & 7;
    const int idx = blockIdx.x >> 3;
    bn = idx % nbn;
    bm = idx / nbn;
  }
  A += (size_t)z * Az;
  B += (size_t)z * Bz;

  // staging: thread covers row (r*64 + srow), 16B at phys col (lane&7)*16;
  // global source col inverse-swizzled (both-sides involution).
  const int srow = w * 8 + (lane >> 3);
  const int scol = ((lane & 7) ^ (lane >> 3)) << 3;  // elems
  const u16* Ab0 = A + (size_t)(bm * 256 + srow) * lda + scol;
  const u16* Ab1 = Ab0 + (size_t)64 * lda;
  const u16* Ab2 = Ab0 + (size_t)128 * lda;
  const u16* Ab3 = Ab0 + (size_t)192 * lda;
  const u16* Bb0 = B + (size_t)(bn * 256 + srow) * ldb + scol;
  const u16* Bb1 = Bb0 + (size_t)64 * ldb;
  const u16* Bb2 = Bb0 + (size_t)128 * ldb;
  const u16* Bb3 = Bb0 + (size_t)192 * ldb;
  char* ldsB = smem + w * 1024;  // wave-uniform stage base; HW adds lane*16

  // fragment read: 8 loop-invariant base pointers + compile-time ds offsets
  const int fr = lane & 15;
  const int fq = lane >> 4;
  const int fx = (fr & 7) << 4;
  const char* pak0 = smem + wr * 16384 + fr * 128 + ((fq * 16) ^ fx);
  const char* pak1 = smem + wr * 16384 + fr * 128 + ((64 + fq * 16) ^ fx);
  const char* pak0b = pak0 + 65536;
  const char* pak1b = pak1 + 65536;
  const char* pbk0 = smem + 32768 + wc * 8192 + fr * 128 + ((fq * 16) ^ fx);
  const char* pbk1 = smem + 32768 + wc * 8192 + fr * 128 + ((64 + fq * 16) ^ fx);
  const char* pbk0b = pbk0 + 65536;
  const char* pbk1b = pbk1 + 65536;

  f32x4 acc0[4][4] = {};  // mh=0 rows
  f32x4 acc1[4][4] = {};  // mh=1 rows
  short8 afr[2][4], bf0[2][2], bf1[2][2];

  const int half = K >> 7;  // iterations; 2 K-tiles each

  // prologue: tile0 -> buf0 (first 8 loads), tile1 -> buf1
  stage16(Bb0, ldsB + 32768); stage16(Bb1, ldsB + 40960);
  stage16(Bb2, ldsB + 49152); stage16(Bb3, ldsB + 57344);
  stage16(Ab0, ldsB + 0);     stage16(Ab1, ldsB + 8192);
  stage16(Ab2, ldsB + 16384); stage16(Ab3, ldsB + 24576);
  stage16(Bb0 + 64, ldsB + 98304);  stage16(Bb1 + 64, ldsB + 106496);
  stage16(Bb2 + 64, ldsB + 114688); stage16(Bb3 + 64, ldsB + 122880);
  stage16(Ab0 + 64, ldsB + 65536);  stage16(Ab1 + 64, ldsB + 73728);
  stage16(Ab2 + 64, ldsB + 81920);  stage16(Ab3 + 64, ldsB + 90112);
  asm volatile("s_waitcnt vmcnt(8)" ::: "memory");  // tile0 landed
  BAR;

  int kto = 128;  // uniform elem offset of tile kt2 (= 2i+2)
  for (int i = 0; i < half; ++i) {
    const bool st = (i + 1 < half);
    // ph1: Q(t0,m0,n0)
    RDA(pak0, pak1, 0);
    RDB(bf0, pbk0, pbk1, 0);
    BAR; MFMAQ(acc0, 0, bf0); BAR;
    // ph2: Q(t0,m0,n1)
    RDB(bf1, pbk0, pbk1, 1);
    BAR; MFMAQ(acc0, 1, bf1); BAR;
    // ph3: Q(t0,m1,n0); B(t0) slots free after ph2 -> restage
    RDA(pak0, pak1, 1);
    if (st) { stage16(Bb0 + kto, ldsB + 32768); stage16(Bb1 + kto, ldsB + 40960); }
    BAR; MFMAQ(acc1, 0, bf0); BAR;
    // ph4: Q(t0,m1,n1)
    if (st) { stage16(Bb2 + kto, ldsB + 49152); stage16(Bb3 + kto, ldsB + 57344); }
    BAR; MFMAQ(acc1, 1, bf1);
    if (st) { asm volatile("s_waitcnt vmcnt(4)" ::: "memory"); }
    else    { asm volatile("s_waitcnt vmcnt(0)" ::: "memory"); }
    BAR;  // t1 fully landed
    // ph5: Q(t1,m0,n0); A(t0) slots free after ph3 -> restage
    RDA(pak0b, pak1b, 0);
    RDB(bf0, pbk0b, pbk1b, 0);
    if (st) { stage16(Ab0 + kto, ldsB + 0); stage16(Ab1 + kto, ldsB + 8192); }
    BAR; MFMAQ(acc0, 0, bf0); BAR;
    // ph6: Q(t1,m0,n1)
    RDB(bf1, pbk0b, pbk1b, 1);
    if (st) { stage16(Ab2 + kto, ldsB + 16384); stage16(Ab3 + kto, ldsB + 24576); }
    BAR; MFMAQ(acc0, 1, bf1); BAR;
    // ph7: Q(t1,m1,n0); B(t1) slots free after ph6
    RDA(pak0b, pak1b, 1);
    if (st) {
      stage16(Bb0 + kto + 64, ldsB + 98304);  stage16(Bb1 + kto + 64, ldsB + 106496);
      stage16(Bb2 + kto + 64, ldsB + 114688); stage16(Bb3 + kto + 64, ldsB + 122880);
    }
    BAR; MFMAQ(acc1, 0, bf0); BAR;
    // ph8: Q(t1,m1,n1); A(t1) slots free after ph7
    if (st) {
      stage16(Ab0 + kto + 64, ldsB + 65536); stage16(Ab1 + kto + 64, ldsB + 73728);
      stage16(Ab2 + kto + 64, ldsB + 81920); stage16(Ab3 + kto + 64, ldsB + 90112);
    }
    BAR; MFMAQ(acc1, 1, bf1);
    asm volatile("s_waitcnt vmcnt(8)" ::: "memory");  // next t0 landed
    BAR;
    kto += 128;
  }

  // D layout per 16x16 frag: col = fr, row = fq*4 + j.
  const int colb = bn * 256 + wc * 64 + fr;
#pragma unroll
  for (int mh = 0; mh < 2; ++mh) {
    f32x4(&ac)[4][4] = mh ? acc1 : acc0;
    const int rowb = bm * 256 + wr * 128 + mh * 64 + fq * 4;
    if constexpr (MODE == 0) {
      u16* Cb = (u16*)C;
#pragma unroll
      for (int mf = 0; mf < 4; ++mf)
#pragma unroll
        for (int n = 0; n < 4; ++n) {
          const int c = colb + n * 16;
          const float bv = bias[c];
#pragma unroll
          for (int j = 0; j < 4; ++j)
            Cb[(size_t)(rowb + mf * 16 + j) * ldc + c] = f2bf(ac[mf][n][j] + bv);
        }
    } else if constexpr (MODE == 1) {
      u16* Cb = (u16*)C;  // vT [8][1024][2048]
#pragma unroll
      for (int mf = 0; mf < 4; ++mf) {
        const int s0r = rowb + mf * 16;
        const int b_ = s0r >> 11;
        const int s_ = s0r & 2047;
#pragma unroll
        for (int n = 0; n < 4; ++n) {
          const int c = colb + n * 16;
          const float bv = bias[c];
          ushort4 o;
          o.x = f2bf(ac[mf][n][0] + bv);
          o.y = f2bf(ac[mf][n][1] + bv);
          o.z = f2bf(ac[mf][n][2] + bv);
          o.w = f2bf(ac[mf][n][3] + bv);
          *(ushort4*)&Cb[((size_t)b_ * 1024 + c) * 2048 + s_] = o;
        }
      }
    } else if constexpr (MODE == 2) {
      u16* Cb = (u16*)C + (size_t)z * Cz;
#pragma unroll
      for (int mf = 0; mf < 4; ++mf)
#pragma unroll
        for (int n = 0; n < 4; ++n) {
          const int c = colb + n * 16;
#pragma unroll
          for (int j = 0; j < 4; ++j)
            Cb[(size_t)(rowb + mf * 16 + j) * ldc + c] =
                f2bf(ac[mf][n][j] * 0.03125f);
        }
    } else {
      float* Cb = (float*)C + (size_t)z * Cz;
#pragma unroll
      for (int mf = 0; mf < 4; ++mf)
#pragma unroll
        for (int n = 0; n < 4; ++n) {
          const int c = colb + n * 16;
#pragma unroll
          for (int j = 0; j < 4; ++j)
            Cb[(size_t)(rowb + mf * 16 + j) * ldc + c] = ac[mf][n][j];
        }
    }
  }
}

// Masked row softmax over bf16 scores [2048]; writes P bf16 in place.
__global__ __launch_bounds__(256) void softmax_mask(u16* __restrict__ scores,
                                                    const int* __restrict__ mask) {
  const int row = blockIdx.x, b = blockIdx.y;
  const int t = threadIdx.x, lane = t & 63, w = t >> 6;
  u16* sc = scores + ((size_t)(b * 2048 + row) << 11);
  const int mrow = mask[b * 2048 + row];
  if (mrow == 0) {
    const u16 pv = f2bf(1.0f / 2048.0f);
    ushort4 o;
    o.x = o.y = o.z = o.w = pv;
    *(ushort4*)&sc[t * 8] = o;
    *(ushort4*)&sc[t * 8 + 4] = o;
    return;
  }
  const ushort4 h0 = ((const ushort4*)sc)[t * 2];
  const ushort4 h1 = ((const ushort4*)sc)[t * 2 + 1];
  const int4 m0 = ((const int4*)(mask + b * 2048))[t * 2];
  const int4 m1 = ((const int4*)(mask + b * 2048))[t * 2 + 1];
  float v[8] = {bf2f(h0.x), bf2f(h0.y), bf2f(h0.z), bf2f(h0.w),
                bf2f(h1.x), bf2f(h1.y), bf2f(h1.z), bf2f(h1.w)};
  const int mm[8] = {m0.x, m0.y, m0.z, m0.w, m1.x, m1.y, m1.z, m1.w};
  float lmax = -3.0e38f;
#pragma unroll
  for (int i = 0; i < 8; ++i)
    if (mm[i]) lmax = fmaxf(lmax, v[i]);
#pragma unroll
  for (int off = 32; off >= 1; off >>= 1) lmax = fmaxf(lmax, __shfl_xor(lmax, off));
  __shared__ float red[8];
  if (lane == 0) red[w] = lmax;
  __syncthreads();
  const float bmax = fmaxf(fmaxf(red[0], red[1]), fmaxf(red[2], red[3]));
  float e[8];
  float lsum = 0.f;
#pragma unroll
  for (int i = 0; i < 8; ++i) {
    e[i] = mm[i] ? __expf(v[i] - bmax) : 0.f;
    lsum += e[i];
  }
#pragma unroll
  for (int off = 32; off >= 1; off >>= 1) lsum += __shfl_xor(lsum, off);
  if (lane == 0) red[4 + w] = lsum;
  __syncthreads();
  const float inv = 1.0f / ((red[4] + red[5]) + (red[6] + red[7]));
  ushort4 o0, o1;
  o0.x = f2bf(e[0] * inv); o0.y = f2bf(e[1] * inv);
  o0.z = f2bf(e[2] * inv); o0.w = f2bf(e[3] * inv);
  o1.x = f2bf(e[4] * inv); o1.y = f2bf(e[5] * inv);
  o1.z = f2bf(e[6] * inv); o1.w = f2bf(e[7] * inv);
  *(ushort4*)&sc[t * 8] = o0;
  *(ushort4*)&sc[t * 8 + 4] = o1;
}

extern "C" void kernel_launch(void* const* d_in, const int* in_sizes, int n_in,
                              void* d_out, int out_size, void* d_ws, size_t ws_size,
                              hipStream_t stream) {
  const float* in_q = (const float*)d_in[0];
  const float* in_k = (const float*)d_in[1];
  const float* in_v = (const float*)d_in[2];
  const int* mask = (const int*)d_in[3];
  const float* Wq = (const float*)d_in[4];
  const float* bq = (const float*)d_in[5];
  const float* Wk = (const float*)d_in[6];
  const float* bk = (const float*)d_in[7];
  const float* Wv = (const float*)d_in[8];
  const float* bv = (const float*)d_in[9];

  char* ws = (char*)d_ws;
  const size_t SZ = (size_t)16384 * 1024 * 2;  // 32M bytes
  u16* qb = (u16*)(ws);
  u16* kb = (u16*)(ws + SZ);
  u16* vT = (u16*)(ws + 2 * SZ);
  u16* Aq = (u16*)(ws + 3 * SZ);
  u16* Ak = (u16*)(ws + 4 * SZ);
  u16* Av = (u16*)(ws + 5 * SZ);
  u16* WqT = (u16*)(ws + 6 * SZ);
  u16* WkT = WqT + 1024 * 1024;
  u16* WvT = WkT + 1024 * 1024;
  u16* scores = (u16*)(ws + 3 * SZ);  // bf16 [8][2048][2048], overlays A region

  // 1) converts
  const int n4 = 16384 * 1024 / 4;
  cvt<<<2048, 256, 0, stream>>>((const float4*)in_q, (ushort4*)Aq, n4);
  cvt<<<2048, 256, 0, stream>>>((const float4*)in_k, (ushort4*)Ak, n4);
  cvt<<<2048, 256, 0, stream>>>((const float4*)in_v, (ushort4*)Av, n4);
  dim3 wtb(32, 8);
  wtrans<<<dim3(32, 32), wtb, 0, stream>>>(Wq, WqT);
  wtrans<<<dim3(32, 32), wtb, 0, stream>>>(Wk, WkT);
  wtrans<<<dim3(32, 32), wtb, 0, stream>>>(Wv, WvT);

  // 2) projections: 64 bm x 4 bn = 256 blocks (chunked XCD map)
  gemm8p<0, 0><<<dim3(256, 1), 512, 0, stream>>>(Aq, WqT, bq, qb, 1024, 1024,
                                                 1024, 1024, 4, 0, 0, 0);
  gemm8p<0, 0><<<dim3(256, 1), 512, 0, stream>>>(Ak, WkT, bk, kb, 1024, 1024,
                                                 1024, 1024, 4, 0, 0, 0);
  gemm8p<1, 0><<<dim3(256, 1), 512, 0, stream>>>(Av, WvT, bv, vT, 1024, 1024,
                                                 1024, 2048, 4, 0, 0, 0);

  // 3) scores[b] = q[b] k[b]^T / 32 ; batch-per-XCD, 8bm x 8bn x 8b = 512
  gemm8p<2, 1><<<dim3(512, 1), 512, 0, stream>>>(
      qb, kb, nullptr, scores, 1024, 1024, 1024, 2048, 8,
      (size_t)2048 * 1024, (size_t)2048 * 1024, (size_t)2048 * 2048);

  // 4) masked softmax -> P bf16 in place
  softmax_mask<<<dim3(2048, 8), 256, 0, stream>>>(scores, mask);

  // 5) out[b] = P[b] vT[b]^T ; batch-per-XCD, 8bm x 4bn x 8b = 256
  gemm8p<3, 1><<<dim3(256, 1), 512, 0, stream>>>(
      scores, vT, nullptr, d_out, 2048, 2048, 2048, 1024, 4,
      (size_t)2048 * 2048, (size_t)1024 * 2048, (size_t)2048 * 1024);
}

// Round 7
// 334.338 us; speedup vs baseline: 1.0263x; 1.0104x over previous
//
#include <hip/hip_runtime.h>
#include <stdint.h>

// SelfAttentionV3: out = softmax(mask(QK^T/32)) V, Q=Xq Wq+bq etc.
// B=8, S=2048, D=1024. GEMMs: bf16 MFMA, 256x256 tile, BK=64, 16 micro-phase
// schedule: every ds_read issued one phase ahead (register-rotation, no extra
// VGPRs), counted vmcnt, XOR-swizzled LDS, setprio, batch->XCD mapping.
//
// ws layout (bytes):
//   [0,    32M)  q_bf16  [16384][1024]
//   [32M,  64M)  k_bf16  [16384][1024]
//   [64M,  96M)  vT_bf16 [8][1024][2048]
//   [96M, 192M)  A_bf16 converted inputs (dead after projections)
//   [192M,198M)  WT_bf16 transposed weights (dead after projections)
//   [96M, 163M)  scores/P bf16 [8][2048][2048] (overlays A region)

typedef unsigned short u16;
typedef __attribute__((ext_vector_type(8))) short short8;
typedef __attribute__((ext_vector_type(4))) float f32x4;

__device__ __forceinline__ u16 f2bf(float x) {
  unsigned u = __float_as_uint(x);
  return (u16)((u + 0x7FFFu + ((u >> 16) & 1u)) >> 16);  // RNE
}
__device__ __forceinline__ float bf2f(u16 h) {
  return __uint_as_float(((unsigned)h) << 16);
}

__device__ __forceinline__ void stage16(const void* g, void* l) {
  const __attribute__((address_space(1))) uint32_t* gp =
      (const __attribute__((address_space(1))) uint32_t*)(uintptr_t)g;
  __attribute__((address_space(3))) uint32_t* lp =
      (__attribute__((address_space(3))) uint32_t*)(uintptr_t)l;
  __builtin_amdgcn_global_load_lds(gp, lp, 16, 0, 0);
}

__device__ __forceinline__ short8 ld8(const char* p, int off) {
  return *(const short8*)(p + off);  // off compile-time -> ds offset: imm
}

__global__ __launch_bounds__(256) void cvt(const float4* __restrict__ in,
                                           ushort4* __restrict__ out, int n4) {
  int stride = gridDim.x * blockDim.x;
  for (int i = blockIdx.x * blockDim.x + threadIdx.x; i < n4; i += stride) {
    float4 f = in[i];
    ushort4 o;
    o.x = f2bf(f.x); o.y = f2bf(f.y); o.z = f2bf(f.z); o.w = f2bf(f.w);
    out[i] = o;
  }
}

__global__ __launch_bounds__(256) void wtrans(const float* __restrict__ W,
                                              u16* __restrict__ WT) {
  __shared__ float tile[32][33];
  const int tx = threadIdx.x, ty = threadIdx.y;  // 32 x 8
  const int d0 = blockIdx.y * 32, n0 = blockIdx.x * 32;
#pragma unroll
  for (int i = 0; i < 4; ++i)
    tile[ty + 8 * i][tx] = W[(size_t)(d0 + ty + 8 * i) * 1024 + n0 + tx];
  __syncthreads();
#pragma unroll
  for (int i = 0; i < 4; ++i)
    WT[(size_t)(n0 + ty + 8 * i) * 1024 + d0 + tx] = f2bf(tile[tx][ty + 8 * i]);
}

// ---- 16-micro-phase 256x256 GEMM: C = A * B^T, both bf16 K-contiguous ----
// 512 thr = 8 waves (2M x 4N), wave tile 128x64, BK=64, 2 K-tile LDS bufs.
// Per K-tile: 8 phases x 8 MFMA; A quads (2 mf-frags) rotate through 2 reg
// sets (aA/aB), B halves through bf0/bf1; every read issued 1+ phase ahead.
// Swizzle: phys_colByte = logical ^ ((row&7)<<4), both-sides involution.

#define BAR __builtin_amdgcn_s_barrier()

#define RDQ(DST, K0, K1, QOFF)                              \
  {                                                         \
    DST[0][0] = ld8(K0, (QOFF));                            \
    DST[0][1] = ld8(K0, (QOFF) + 2048);                     \
    DST[1][0] = ld8(K1, (QOFF));                            \
    DST[1][1] = ld8(K1, (QOFF) + 2048);                     \
  }

#define RDB(DST, K0, K1, NH)                                \
  {                                                         \
    DST[0][0] = ld8(K0, (NH) * 4096);                       \
    DST[0][1] = ld8(K0, (NH) * 4096 + 2048);                \
    DST[1][0] = ld8(K1, (NH) * 4096);                       \
    DST[1][1] = ld8(K1, (NH) * 4096 + 2048);                \
  }

#define MQ(ACC, MB, NH, A2, B2)                                          \
  __builtin_amdgcn_s_setprio(1);                                         \
  {                                                                      \
    _Pragma("unroll") for (int ks_ = 0; ks_ < 2; ++ks_)                  \
        _Pragma("unroll") for (int m_ = 0; m_ < 2; ++m_)                 \
            _Pragma("unroll") for (int nf_ = 0; nf_ < 2; ++nf_)          \
                ACC[(MB) + m_][(NH) * 2 + nf_] =                         \
                    __builtin_amdgcn_mfma_f32_16x16x32_bf16(             \
                        A2[ks_][m_], B2[ks_][nf_],                       \
                        ACC[(MB) + m_][(NH) * 2 + nf_], 0, 0, 0);        \
  }                                                                      \
  __builtin_amdgcn_s_setprio(0);

template <int MODE, int GMAP>
__global__ __launch_bounds__(512, 2) void gemm8p(
    const u16* __restrict__ A, const u16* __restrict__ B,
    const float* __restrict__ bias, void* __restrict__ C,
    int K, int lda, int ldb, int ldc, int nbn,
    size_t Az, size_t Bz, size_t Cz) {
  __shared__ __attribute__((aligned(16))) char smem[131072];
  const int tid = threadIdx.x;
  const int lane = tid & 63;
  const int w = tid >> 6;     // 0..7
  const int wr = w >> 2;      // 0..1 (M)
  const int wc = w & 3;       // 0..3 (N)

  int bm, bn, z;
  if constexpr (GMAP == 0) {
    const int nwg = gridDim.x;
    const int cpx = nwg >> 3;
    int flat = blockIdx.x;
    flat = (flat & 7) * cpx + (flat >> 3);
    bn = flat % nbn;
    bm = flat / nbn;
    z = blockIdx.y;
  } else {
    z = blockIdx.x & 7;
    const int idx = blockIdx.x >> 3;
    bn = idx % nbn;
    bm = idx / nbn;
  }
  A += (size_t)z * Az;
  B += (size_t)z * Bz;

  // staging: thread covers row (group*64 + srow), 16B at phys col (lane&7)*16;
  // global source col inverse-swizzled (both-sides involution).
  const int srow = w * 8 + (lane >> 3);
  const int scol = ((lane & 7) ^ (lane >> 3)) << 3;  // elems
  const u16* Ab0 = A + (size_t)(bm * 256 + srow) * lda + scol;
  const u16* Ab1 = Ab0 + (size_t)64 * lda;
  const u16* Ab2 = Ab0 + (size_t)128 * lda;
  const u16* Ab3 = Ab0 + (size_t)192 * lda;
  const u16* Bb0 = B + (size_t)(bn * 256 + srow) * ldb + scol;
  const u16* Bb1 = Bb0 + (size_t)64 * ldb;
  const u16* Bb2 = Bb0 + (size_t)128 * ldb;
  const u16* Bb3 = Bb0 + (size_t)192 * ldb;
  char* ldsW = smem + w * 1024;  // wave-uniform stage base; HW adds lane*16

  // fragment read: loop-invariant base pointers + compile-time ds offsets
  const int fr = lane & 15;
  const int fq = lane >> 4;
  const int fx = (fr & 7) << 4;
  const char* pak0 = smem + wr * 16384 + fr * 128 + ((fq * 16) ^ fx);
  const char* pak1 = smem + wr * 16384 + fr * 128 + ((64 + fq * 16) ^ fx);
  const char* pak0b = pak0 + 65536;
  const char* pak1b = pak1 + 65536;
  const char* pbk0 = smem + 32768 + wc * 8192 + fr * 128 + ((fq * 16) ^ fx);
  const char* pbk1 = smem + 32768 + wc * 8192 + fr * 128 + ((64 + fq * 16) ^ fx);
  const char* pbk0b = pbk0 + 65536;
  const char* pbk1b = pbk1 + 65536;

  f32x4 acc0[4][4] = {};  // mh=0 (mf 0..3)
  f32x4 acc1[4][4] = {};  // mh=1 (mf 4..7)
  short8 aA[2][2], aB[2][2], bf0[2][2], bf1[2][2];

  const int half = K >> 7;  // iterations; 2 K-tiles each

  // prologue: A(t0),B(t0) -> buf0; B(t1) -> buf1; A(t1)|0 -> buf1
  stage16(Ab0, ldsW + 0);     stage16(Ab1, ldsW + 8192);
  stage16(Ab2, ldsW + 16384); stage16(Ab3, ldsW + 24576);
  stage16(Bb0, ldsW + 32768); stage16(Bb1, ldsW + 40960);
  stage16(Bb2, ldsW + 49152); stage16(Bb3, ldsW + 57344);
  stage16(Bb0 + 64, ldsW + 98304);  stage16(Bb1 + 64, ldsW + 106496);
  stage16(Bb2 + 64, ldsW + 114688); stage16(Bb3 + 64, ldsW + 122880);
  stage16(Ab0 + 64, ldsW + 65536);
  asm volatile("s_waitcnt vmcnt(5)" ::: "memory");  // t0 landed
  BAR;
  RDQ(aA, pak0, pak1, 0);        // q0(t0)
  RDB(bf0, pbk0, pbk1, 0);       // Bn0(t0)

  int koff = 0;
  for (int i = 0; i < half; ++i) {
    const bool st = (i + 1 < half);
    const int o1 = koff + 64, o2 = koff + 128, o3 = koff + 192;

    // ================= half 0: tile t0 (buf0) =================
    // p1: (q0, Bn0)
    RDB(bf1, pbk0, pbk1, 1);
    BAR;
    stage16(Ab1 + o1, ldsW + 65536 + 8192);   // A(t1)|1
    MQ(acc0, 0, 0, aA, bf0);
    // p2: (q0, Bn1)
    RDQ(aB, pak0, pak1, 4096);
    BAR;
    stage16(Ab2 + o1, ldsW + 65536 + 16384);  // A(t1)|2
    MQ(acc0, 0, 1, aA, bf1);
    // p3: (q1, Bn0)
    BAR;
    stage16(Ab3 + o1, ldsW + 65536 + 24576);  // A(t1)|3
    MQ(acc0, 2, 0, aB, bf0);
    // p4: (q1, Bn1)
    RDQ(aA, pak0, pak1, 8192);
    BAR;
    if (st) stage16(Bb0 + o2, ldsW + 32768);  // B(t2)|0
    MQ(acc0, 2, 1, aB, bf1);
    // p5: (q2, Bn0)
    BAR;
    if (st) stage16(Bb1 + o2, ldsW + 40960);
    MQ(acc1, 0, 0, aA, bf0);
    // p6: (q2, Bn1)
    RDQ(aB, pak0, pak1, 12288);
    BAR;
    if (st) stage16(Bb2 + o2, ldsW + 49152);
    MQ(acc1, 0, 1, aA, bf1);
    // p7: (q3, Bn0)
    BAR;
    if (st) stage16(Bb3 + o2, ldsW + 57344);
    MQ(acc1, 2, 0, aB, bf0);
    if (st) { asm volatile("s_waitcnt vmcnt(4)" ::: "memory"); }
    else    { asm volatile("s_waitcnt vmcnt(0)" ::: "memory"); }
    // p8: (q3, Bn1); t1 landed -> issue its first reads
    BAR;
    RDQ(aA, pak0b, pak1b, 0);      // q0(t1)
    RDB(bf0, pbk0b, pbk1b, 0);     // Bn0(t1)
    if (st) stage16(Ab0 + o2, ldsW + 0);      // A(t2)|0
    MQ(acc1, 2, 1, aB, bf1);

    // ================= half 1: tile t1 (buf1) =================
    // p1
    RDB(bf1, pbk0b, pbk1b, 1);
    BAR;
    if (st) stage16(Ab1 + o2, ldsW + 8192);   // A(t2)|1
    MQ(acc0, 0, 0, aA, bf0);
    // p2
    RDQ(aB, pak0b, pak1b, 4096);
    BAR;
    if (st) stage16(Ab2 + o2, ldsW + 16384);  // A(t2)|2
    MQ(acc0, 0, 1, aA, bf1);
    // p3
    BAR;
    if (st) stage16(Ab3 + o2, ldsW + 24576);  // A(t2)|3
    MQ(acc0, 2, 0, aB, bf0);
    // p4
    RDQ(aA, pak0b, pak1b, 8192);
    BAR;
    if (st) stage16(Bb0 + o3, ldsW + 98304);  // B(t3)|0
    MQ(acc0, 2, 1, aB, bf1);
    // p5
    BAR;
    if (st) stage16(Bb1 + o3, ldsW + 106496);
    MQ(acc1, 0, 0, aA, bf0);
    // p6
    RDQ(aB, pak0b, pak1b, 12288);
    BAR;
    if (st) stage16(Bb2 + o3, ldsW + 114688);
    MQ(acc1, 0, 1, aA, bf1);
    // p7
    BAR;
    if (st) stage16(Bb3 + o3, ldsW + 122880);
    MQ(acc1, 2, 0, aB, bf0);
    if (st) { asm volatile("s_waitcnt vmcnt(4)" ::: "memory"); }
    else    { asm volatile("s_waitcnt vmcnt(0)" ::: "memory"); }
    // p8: t2 landed -> issue its first reads
    BAR;
    RDQ(aA, pak0, pak1, 0);        // q0(t2)
    RDB(bf0, pbk0, pbk1, 0);       // Bn0(t2)
    if (st) stage16(Ab0 + o3, ldsW + 65536);  // A(t3)|0
    MQ(acc1, 2, 1, aB, bf1);

    koff += 128;
  }

  // D layout per 16x16 frag: col = fr, row = fq*4 + j.
  const int colb = bn * 256 + wc * 64 + fr;
#pragma unroll
  for (int mh = 0; mh < 2; ++mh) {
    f32x4(&ac)[4][4] = mh ? acc1 : acc0;
    const int rowb = bm * 256 + wr * 128 + mh * 64 + fq * 4;
    if constexpr (MODE == 0) {
      u16* Cb = (u16*)C;
#pragma unroll
      for (int mf = 0; mf < 4; ++mf)
#pragma unroll
        for (int n = 0; n < 4; ++n) {
          const int c = colb + n * 16;
          const float bv = bias[c];
#pragma unroll
          for (int j = 0; j < 4; ++j)
            Cb[(size_t)(rowb + mf * 16 + j) * ldc + c] = f2bf(ac[mf][n][j] + bv);
        }
    } else if constexpr (MODE == 1) {
      u16* Cb = (u16*)C;  // vT [8][1024][2048]
#pragma unroll
      for (int mf = 0; mf < 4; ++mf) {
        const int s0r = rowb + mf * 16;
        const int b_ = s0r >> 11;
        const int s_ = s0r & 2047;
#pragma unroll
        for (int n = 0; n < 4; ++n) {
          const int c = colb + n * 16;
          const float bv = bias[c];
          ushort4 o;
          o.x = f2bf(ac[mf][n][0] + bv);
          o.y = f2bf(ac[mf][n][1] + bv);
          o.z = f2bf(ac[mf][n][2] + bv);
          o.w = f2bf(ac[mf][n][3] + bv);
          *(ushort4*)&Cb[((size_t)b_ * 1024 + c) * 2048 + s_] = o;
        }
      }
    } else if constexpr (MODE == 2) {
      u16* Cb = (u16*)C + (size_t)z * Cz;
#pragma unroll
      for (int mf = 0; mf < 4; ++mf)
#pragma unroll
        for (int n = 0; n < 4; ++n) {
          const int c = colb + n * 16;
#pragma unroll
          for (int j = 0; j < 4; ++j)
            Cb[(size_t)(rowb + mf * 16 + j) * ldc + c] =
                f2bf(ac[mf][n][j] * 0.03125f);
        }
    } else {
      float* Cb = (float*)C + (size_t)z * Cz;
#pragma unroll
      for (int mf = 0; mf < 4; ++mf)
#pragma unroll
        for (int n = 0; n < 4; ++n) {
          const int c = colb + n * 16;
#pragma unroll
          for (int j = 0; j < 4; ++j)
            Cb[(size_t)(rowb + mf * 16 + j) * ldc + c] = ac[mf][n][j];
        }
    }
  }
}

// Masked row softmax over bf16 scores [2048]; writes P bf16 in place.
__global__ __launch_bounds__(256) void softmax_mask(u16* __restrict__ scores,
                                                    const int* __restrict__ mask) {
  const int row = blockIdx.x, b = blockIdx.y;
  const int t = threadIdx.x, lane = t & 63, w = t >> 6;
  u16* sc = scores + ((size_t)(b * 2048 + row) << 11);
  const int mrow = mask[b * 2048 + row];
  if (mrow == 0) {
    const u16 pv = f2bf(1.0f / 2048.0f);
    ushort4 o;
    o.x = o.y = o.z = o.w = pv;
    *(ushort4*)&sc[t * 8] = o;
    *(ushort4*)&sc[t * 8 + 4] = o;
    return;
  }
  const ushort4 h0 = ((const ushort4*)sc)[t * 2];
  const ushort4 h1 = ((const ushort4*)sc)[t * 2 + 1];
  const int4 m0 = ((const int4*)(mask + b * 2048))[t * 2];
  const int4 m1 = ((const int4*)(mask + b * 2048))[t * 2 + 1];
  float v[8] = {bf2f(h0.x), bf2f(h0.y), bf2f(h0.z), bf2f(h0.w),
                bf2f(h1.x), bf2f(h1.y), bf2f(h1.z), bf2f(h1.w)};
  const int mm[8] = {m0.x, m0.y, m0.z, m0.w, m1.x, m1.y, m1.z, m1.w};
  float lmax = -3.0e38f;
#pragma unroll
  for (int i = 0; i < 8; ++i)
    if (mm[i]) lmax = fmaxf(lmax, v[i]);
#pragma unroll
  for (int off = 32; off >= 1; off >>= 1) lmax = fmaxf(lmax, __shfl_xor(lmax, off));
  __shared__ float red[8];
  if (lane == 0) red[w] = lmax;
  __syncthreads();
  const float bmax = fmaxf(fmaxf(red[0], red[1]), fmaxf(red[2], red[3]));
  float e[8];
  float lsum = 0.f;
#pragma unroll
  for (int i = 0; i < 8; ++i) {
    e[i] = mm[i] ? __expf(v[i] - bmax) : 0.f;
    lsum += e[i];
  }
#pragma unroll
  for (int off = 32; off >= 1; off >>= 1) lsum += __shfl_xor(lsum, off);
  if (lane == 0) red[4 + w] = lsum;
  __syncthreads();
  const float inv = 1.0f / ((red[4] + red[5]) + (red[6] + red[7]));
  ushort4 o0, o1;
  o0.x = f2bf(e[0] * inv); o0.y = f2bf(e[1] * inv);
  o0.z = f2bf(e[2] * inv); o0.w = f2bf(e[3] * inv);
  o1.x = f2bf(e[4] * inv); o1.y = f2bf(e[5] * inv);
  o1.z = f2bf(e[6] * inv); o1.w = f2bf(e[7] * inv);
  *(ushort4*)&sc[t * 8] = o0;
  *(ushort4*)&sc[t * 8 + 4] = o1;
}

extern "C" void kernel_launch(void* const* d_in, const int* in_sizes, int n_in,
                              void* d_out, int out_size, void* d_ws, size_t ws_size,
                              hipStream_t stream) {
  const float* in_q = (const float*)d_in[0];
  const float* in_k = (const float*)d_in[1];
  const float* in_v = (const float*)d_in[2];
  const int* mask = (const int*)d_in[3];
  const float* Wq = (const float*)d_in[4];
  const float* bq = (const float*)d_in[5];
  const float* Wk = (const float*)d_in[6];
  const float* bk = (const float*)d_in[7];
  const float* Wv = (const float*)d_in[8];
  const float* bv = (const float*)d_in[9];

  char* ws = (char*)d_ws;
  const size_t SZ = (size_t)16384 * 1024 * 2;  // 32M bytes
  u16* qb = (u16*)(ws);
  u16* kb = (u16*)(ws + SZ);
  u16* vT = (u16*)(ws + 2 * SZ);
  u16* Aq = (u16*)(ws + 3 * SZ);
  u16* Ak = (u16*)(ws + 4 * SZ);
  u16* Av = (u16*)(ws + 5 * SZ);
  u16* WqT = (u16*)(ws + 6 * SZ);
  u16* WkT = WqT + 1024 * 1024;
  u16* WvT = WkT + 1024 * 1024;
  u16* scores = (u16*)(ws + 3 * SZ);  // bf16 [8][2048][2048], overlays A region

  // 1) converts
  const int n4 = 16384 * 1024 / 4;
  cvt<<<2048, 256, 0, stream>>>((const float4*)in_q, (ushort4*)Aq, n4);
  cvt<<<2048, 256, 0, stream>>>((const float4*)in_k, (ushort4*)Ak, n4);
  cvt<<<2048, 256, 0, stream>>>((const float4*)in_v, (ushort4*)Av, n4);
  dim3 wtb(32, 8);
  wtrans<<<dim3(32, 32), wtb, 0, stream>>>(Wq, WqT);
  wtrans<<<dim3(32, 32), wtb, 0, stream>>>(Wk, WkT);
  wtrans<<<dim3(32, 32), wtb, 0, stream>>>(Wv, WvT);

  // 2) projections: 64 bm x 4 bn = 256 blocks (chunked XCD map)
  gemm8p<0, 0><<<dim3(256, 1), 512, 0, stream>>>(Aq, WqT, bq, qb, 1024, 1024,
                                                 1024, 1024, 4, 0, 0, 0);
  gemm8p<0, 0><<<dim3(256, 1), 512, 0, stream>>>(Ak, WkT, bk, kb, 1024, 1024,
                                                 1024, 1024, 4, 0, 0, 0);
  gemm8p<1, 0><<<dim3(256, 1), 512, 0, stream>>>(Av, WvT, bv, vT, 1024, 1024,
                                                 1024, 2048, 4, 0, 0, 0);

  // 3) scores[b] = q[b] k[b]^T / 32 ; batch-per-XCD, 8bm x 8bn x 8b = 512
  gemm8p<2, 1><<<dim3(512, 1), 512, 0, stream>>>(
      qb, kb, nullptr, scores, 1024, 1024, 1024, 2048, 8,
      (size_t)2048 * 1024, (size_t)2048 * 1024, (size_t)2048 * 2048);

  // 4) masked softmax -> P bf16 in place
  softmax_mask<<<dim3(2048, 8), 256, 0, stream>>>(scores, mask);

  // 5) out[b] = P[b] vT[b]^T ; batch-per-XCD, 8bm x 4bn x 8b = 256
  gemm8p<3, 1><<<dim3(256, 1), 512, 0, stream>>>(
      scores, vT, nullptr, d_out, 2048, 2048, 2048, 1024, 4,
      (size_t)2048 * 2048, (size_t)1024 * 2048, (size_t)2048 * 1024);
}